// Round 1
// baseline (141.733 us; speedup 1.0000x reference)
//
#include <hip/hip_runtime.h>

#define HD 64       // HIDDEN_DIM
#define NE 512      // N_EMBEDS
#define HW 1024     // 32*32 spatial positions per batch image

typedef float f32x2 __attribute__((ext_vector_type(2)));
typedef float f32x4 __attribute__((ext_vector_type(4)));

// ---------------------------------------------------------------------------
// Prep (130 blocks x 256):
//  blk 0..127 : epT[c][k] = -2 * e[k][c]   (transposed, code-major rows)
//               -2 fold bit-exact (pow2 scale commutes with fp32 rounding).
//  blk 128/129: esq[k] = np.sum(e[k]*e[k]), numpy pairwise-8, no contraction.
//  Verified absmax==0.0 R1-R10.
// ---------------------------------------------------------------------------
__global__ __launch_bounds__(256) void vq_prep_kernel(const float* __restrict__ e,
                                                      float* __restrict__ epT,
                                                      float* __restrict__ esq) {
  const int blk = blockIdx.x;
  if (blk < 128) {
    const int t = blk * 256 + threadIdx.x;     // 0..32767
    const int c = t >> 9, k = t & 511;
    epT[t] = -2.0f * e[k * HD + c];
  } else {
    const int k = (blk - 128) * 256 + threadIdx.x;   // 0..511
    const float4* __restrict__ rowv = reinterpret_cast<const float4*>(e + k * HD);
    float row[HD];
    #pragma unroll
    for (int i = 0; i < 16; ++i) {
      const float4 v = rowv[i];
      row[4 * i + 0] = v.x; row[4 * i + 1] = v.y;
      row[4 * i + 2] = v.z; row[4 * i + 3] = v.w;
    }
    float result;
    {
      #pragma clang fp contract(off)
      float r[8];
      #pragma unroll
      for (int j = 0; j < 8; ++j) r[j] = row[j] * row[j];
      #pragma unroll
      for (int i = 8; i < HD; i += 8) {
        #pragma unroll
        for (int j = 0; j < 8; ++j) r[j] = r[j] + row[i + j] * row[i + j];
      }
      result = ((r[0] + r[1]) + (r[2] + r[3])) + ((r[4] + r[5]) + (r[6] + r[7]));
    }
    esq[k] = result;
  }
}

// ---------------------------------------------------------------------------
// Main R12: 2048 blocks x 256 (4 waves). Block = 32 positions x 512 codes.
//
// R11 was LDS-pipe bound: 4 ds_read_b128 per 32 pk_fma -> 8192 LDS instr/CU
// x 12 cyc ~ 41 us (62% of the 66 us dispatch). The LDS reads were mostly
// duplication (x 16-way, e 4-way across lanes) and instruction cost is
// per-wave-instr, so staging bought nothing: x is 8 KB/block (L1-fits) and
// epT is 128 KB (L2-hot, ~13 TB/s aggregate demand << 34.5 TB/s L2).
//
// R12: read operands DIRECTLY from global per c (4 global_load_dwordx4 per
// wave-c; TA merges duplicate-address lanes). LDS pipe emptied except the
// tiny argmin combine. VMEM issue ~8192 instr/CU x ~4 cyc ~ 13.7 us now
// balances the pk_fma floor (13.7 us/SIMD). No DMA, no chunk barriers
// (2 syncthreads total), VGPR ~110 -> 4 waves/SIMD hides L2 latency; A/B
// software pipeline keeps loads 1 c-pair ahead.
//
// Bit-exactness preserved: identical v_pk_fma_f32 chain (one fma per c,
// c ascending 0..63, positions pk-paired, e broadcast via op_sel), identical
// xsq/esq pairwise-8 numpy sums, identical (xsq+esq)+acc epilogue and
// first-index-wins slot combine as the R1-R10-verified kernel.
//
// Geometry (unchanged): wave = code quarter wc. Lane: p=lane&3 -> positions
// 8p..8p+7 (4 pairs); q=lane>>2 -> codes kb=128wc+8q..+7. Slot s=16wc+q
// covers codes [8s,8s+8); ascending-s combine == np.argmin first-index-wins.
// ---------------------------------------------------------------------------
__global__ __launch_bounds__(256)
__attribute__((amdgpu_waves_per_eu(4)))
void vq_main_kernel(const float* __restrict__ x,
                    const float* __restrict__ epT,
                    const float* __restrict__ esq,
                    const float* __restrict__ e,
                    float* __restrict__ out) {
  __shared__ float smin[64 * 32];      // 8 KB  [slot][pos]
  __shared__ int   sidx[64 * 32];      // 8 KB
  __shared__ float xsq[32];
  __shared__ int   bcomb[32];

  const int t    = threadIdx.x;
  const int lane = t & 63;
  const int wc   = t >> 6;             // 0..3  wave = code quarter
  const int p    = lane & 3;           // pos-octet group
  const int q    = lane >> 2;          // 0..15 code slot
  const int posb = p * 8;              // lane's 8 positions
  const int kb   = wc * 128 + q * 8;   // lane's 8 codes

  const int blk = blockIdx.x;          // 2048
  const int b   = blk >> 5;
  const int s0  = (blk & 31) << 5;
  const size_t xbase = (size_t)b * (HD * HW) + s0;

  // ---- xsq[pos]: numpy pairwise-8, no contraction (bit-exact), wave 0 only.
  //      Reads global directly (values identical to the old LDS-staged path).
  //      No barrier needed until the epilogue consumes xsq.
  if (t < 32) {
    #pragma clang fp contract(off)
    const float* __restrict__ xp0 = x + xbase + t;
    float r[8];
    #pragma unroll
    for (int j = 0; j < 8; ++j) {
      const float v = xp0[(size_t)j * HW];
      r[j] = v * v;
    }
    #pragma unroll
    for (int i = 8; i < HD; i += 8) {
      #pragma unroll
      for (int j = 0; j < 8; ++j) {
        const float v = xp0[(size_t)(i + j) * HW];
        r[j] = r[j] + v * v;
      }
    }
    xsq[t] = ((r[0] + r[1]) + (r[2] + r[3])) + ((r[4] + r[5]) + (r[6] + r[7]));
  }

  // ---- accumulator: acc2[pos-pair][code j] == -2*cross (fma chain over c)
  f32x2 acc2[4][8];                    // 64 VGPRs
  #pragma unroll
  for (int pi = 0; pi < 4; ++pi)
    #pragma unroll
    for (int j = 0; j < 8; ++j) acc2[pi][j] = (f32x2)(0.f);

#define LOADPAIR(XA, XB, E0, E1, c) do {                                   \
    const float* __restrict__ xr_ = x + xbase + (size_t)(c) * HW;          \
    const float* __restrict__ er_ = epT + (c) * NE;                        \
    (XA) = *reinterpret_cast<const f32x4*>(xr_ + posb);                    \
    (XB) = *reinterpret_cast<const f32x4*>(xr_ + posb + 4);                \
    (E0) = *reinterpret_cast<const f32x4*>(er_ + kb);                      \
    (E1) = *reinterpret_cast<const f32x4*>(er_ + kb + 4);                  \
  } while (0)

#define COMPUTE(XA, XB, E0, E1) do {                                       \
    f32x2 xp[4] = {(XA).lo, (XA).hi, (XB).lo, (XB).hi};                    \
    f32x2 ep[4] = {(E0).lo, (E0).hi, (E1).lo, (E1).hi};                    \
    _Pragma("unroll")                                                      \
    for (int pi = 0; pi < 4; ++pi) {                                       \
      _Pragma("unroll")                                                    \
      for (int jp = 0; jp < 4; ++jp) {                                     \
        /* code 2jp  : e-pair LOW dword broadcast to both halves */        \
        asm("v_pk_fma_f32 %0, %1, %2, %0 op_sel:[0,0,0] op_sel_hi:[1,0,1]" \
            : "+v"(acc2[pi][2 * jp]) : "v"(xp[pi]), "v"(ep[jp]));          \
        /* code 2jp+1: e-pair HIGH dword broadcast to both halves */       \
        asm("v_pk_fma_f32 %0, %1, %2, %0 op_sel:[0,1,0] op_sel_hi:[1,1,1]" \
            : "+v"(acc2[pi][2 * jp + 1]) : "v"(xp[pi]), "v"(ep[jp]));      \
      }                                                                    \
    }                                                                      \
  } while (0)

  // ---- c-loop: A/B 2-stream software pipeline, loads 1 c-pair ahead.
  //      Accumulation order is strictly c = 0,1,2,...,63 (A even, B odd).
  f32x4 xaA, xbA, e0A, e1A, xaB, xbB, e0B, e1B;
  LOADPAIR(xaA, xbA, e0A, e1A, 0);
  LOADPAIR(xaB, xbB, e0B, e1B, 1);
  #pragma unroll 1
  for (int c = 0; c < 62; c += 2) {
    COMPUTE(xaA, xbA, e0A, e1A);
    LOADPAIR(xaA, xbA, e0A, e1A, c + 2);
    COMPUTE(xaB, xbB, e0B, e1B);
    LOADPAIR(xaB, xbB, e0B, e1B, c + 3);
  }
  COMPUTE(xaA, xbA, e0A, e1A);         // c = 62
  COMPUTE(xaB, xbB, e0B, e1B);         // c = 63

#undef LOADPAIR
#undef COMPUTE

  __syncthreads();                     // xsq visible to all waves

  // ---- dist + per-lane argmin (acc == -2*cross complete)
  const float4 xq0 = *reinterpret_cast<const float4*>(&xsq[posb]);
  const float4 xq1 = *reinterpret_cast<const float4*>(&xsq[posb + 4]);
  const float xqv[8] = {xq0.x, xq0.y, xq0.z, xq0.w, xq1.x, xq1.y, xq1.z, xq1.w};
  const float4 eq0 = *reinterpret_cast<const float4*>(esq + kb);
  const float4 eq1 = *reinterpret_cast<const float4*>(esq + kb + 4);
  const float esv[8] = {eq0.x, eq0.y, eq0.z, eq0.w, eq1.x, eq1.y, eq1.z, eq1.w};

  float bestd[8];
  int   besti[8];
  #pragma unroll
  for (int pi = 0; pi < 8; ++pi) {
    bestd[pi] = __builtin_inff();
    besti[pi] = 0;
    const int pr = pi >> 1, ph = pi & 1;        // pair index, half
    #pragma unroll
    for (int j = 0; j < 8; ++j) {               // ascending j: first-index-wins
      const float d = (xqv[pi] + esv[j]) + acc2[pr][j][ph];  // == (xsq+esq) - 2*cross
      if (d < bestd[pi]) { bestd[pi] = d; besti[pi] = kb + j; }
    }
  }

  // ---- combine: slot s = 16wc+q covers codes [8s,8s+8); ascending-s scan
  const int s = wc * 16 + q;
  *reinterpret_cast<float4*>(&smin[s * 32 + posb]) =
      make_float4(bestd[0], bestd[1], bestd[2], bestd[3]);
  *reinterpret_cast<float4*>(&smin[s * 32 + posb + 4]) =
      make_float4(bestd[4], bestd[5], bestd[6], bestd[7]);
  *reinterpret_cast<int4*>(&sidx[s * 32 + posb]) =
      make_int4(besti[0], besti[1], besti[2], besti[3]);
  *reinterpret_cast<int4*>(&sidx[s * 32 + posb + 4]) =
      make_int4(besti[4], besti[5], besti[6], besti[7]);
  __syncthreads();
  if (t < 32) {
    float bd = smin[t];
    int   bi = sidx[t];
    #pragma unroll
    for (int ss = 1; ss < 64; ++ss) {
      const float d = smin[ss * 32 + t];
      if (d < bd) { bd = d; bi = sidx[ss * 32 + t]; }
    }
    bcomb[t] = bi;
  }
  __syncthreads();

  // ---- gather winning codebook row (L2-hot), coalesced stores
  {
    const int pos = t & 31, cr = t >> 5;
    const int idx = bcomb[pos];
    const float* __restrict__ eq = e + idx * HD;
    #pragma unroll
    for (int i = 0; i < 8; ++i) {
      const int c = cr + 8 * i;
      out[xbase + (size_t)c * HW + pos] = eq[c];
    }
  }
}

extern "C" void kernel_launch(void* const* d_in, const int* in_sizes, int n_in,
                              void* d_out, int out_size, void* d_ws, size_t ws_size,
                              hipStream_t stream) {
  const float* x = (const float*)d_in[0];   // (64, 64, 32, 32) fp32
  const float* e = (const float*)d_in[1];   // (512, 64) fp32
  float* epT = (float*)d_ws;                // 64*512 floats: -2*e transposed
  float* esq = epT + HD * NE;               // 512 floats
  float* out = (float*)d_out;

  vq_prep_kernel<<<130, 256, 0, stream>>>(e, epT, esq);
  vq_main_kernel<<<2048, 256, 0, stream>>>(x, epT, esq, e, out);
}

// Round 2
// 115.984 us; speedup vs baseline: 1.2220x; 1.2220x over previous
//
#include <hip/hip_runtime.h>

#define HD 64       // HIDDEN_DIM
#define NE 512      // N_EMBEDS
#define HW 1024     // 32*32 spatial positions per batch image

typedef float f32x2  __attribute__((ext_vector_type(2)));
typedef float f32x4  __attribute__((ext_vector_type(4)));
typedef float f32x16 __attribute__((ext_vector_type(16)));

// ---------------------------------------------------------------------------
// Prep (130 blocks x 256):
//  blk 0..127 : epT[c][k] = -2 * e[k][c]   (transposed, code-major rows)
//  blk 128/129: esq[k] = np.sum(e[k]*e[k]), numpy pairwise-8, no contraction.
//  Verified absmax==0.0 R1-R12.
// ---------------------------------------------------------------------------
__global__ __launch_bounds__(256) void vq_prep_kernel(const float* __restrict__ e,
                                                      float* __restrict__ epT,
                                                      float* __restrict__ esq) {
  const int blk = blockIdx.x;
  if (blk < 128) {
    const int t = blk * 256 + threadIdx.x;     // 0..32767
    const int c = t >> 9, k = t & 511;
    epT[t] = -2.0f * e[k * HD + c];
  } else {
    const int k = (blk - 128) * 256 + threadIdx.x;   // 0..511
    const float4* __restrict__ rowv = reinterpret_cast<const float4*>(e + k * HD);
    float row[HD];
    #pragma unroll
    for (int i = 0; i < 16; ++i) {
      const float4 v = rowv[i];
      row[4 * i + 0] = v.x; row[4 * i + 1] = v.y;
      row[4 * i + 2] = v.z; row[4 * i + 3] = v.w;
    }
    float result;
    {
      #pragma clang fp contract(off)
      float r[8];
      #pragma unroll
      for (int j = 0; j < 8; ++j) r[j] = row[j] * row[j];
      #pragma unroll
      for (int i = 8; i < HD; i += 8) {
        #pragma unroll
        for (int j = 0; j < 8; ++j) r[j] = r[j] + row[i + j] * row[i + j];
      }
      result = ((r[0] + r[1]) + (r[2] + r[3])) + ((r[4] + r[5]) + (r[6] + r[7]));
    }
    esq[k] = result;
  }
}

// ---------------------------------------------------------------------------
// Main R13: 1024 blocks x 256 (4 waves). Block = 64 positions x 512 codes.
//
// R11 counter analysis: 41 of 66 us was the LDS pipe (4 ds_read_b128 per
// wave-c, both operands lane-duplicated). R13 removes the x reads entirely:
// wave = 16 positions x ALL 512 codes, so x is WAVE-UNIFORM -> one uniform
// 64B load per c (SGPRs, broadcast free as v_pk_fma_f32 src0), and e needs
// only 2 conflict-free ds_read_b128 per wave-c (lane l -> codes
// {4l..4l+3, 256+4l..+3}: 16B-contiguous across lanes).
// Per CU: LDS 2048 b128 x 12cyc = 10.2us, VALU 32.8k cyc = 13.7us -> VALU-
// critical. 1024 blocks halves staging; CC=16 chunks -> 10 barriers total.
//
// Bit-exactness: one IEEE fp32 fma per (pos,code,c), c ascending 0..63
// (pk halves are independent positions); xsq/esq numpy pairwise-8 with the
// exact chain/tree structure of the verified R1-R12 kernels; distance
// (xsq+esq)+acc identical. Argmin: lexicographic (d,idx) merge at every
// stage == np.argmin first-occurrence semantics (exact, order-free).
// ---------------------------------------------------------------------------
__global__ __launch_bounds__(256)
__attribute__((amdgpu_waves_per_eu(3)))
void vq_main_kernel(const float* __restrict__ x,
                    const float* __restrict__ epT,
                    const float* __restrict__ esq,
                    const float* __restrict__ e,
                    float* __restrict__ out) {
  // esbuf: chunk buffer (16 c x 512 codes = 8192 words) overlaid after the
  // last compute barrier by the combine scratch (4 waves x 64 lanes x 36 w).
  __shared__ float esbuf[4 * 64 * 36];   // 9216 words = 36.0 KB
  __shared__ float part[512];            // 2 KB   [w][qq][pi] (d,idx) pairs
  __shared__ float sp[256];              // 1 KB   [g][pos] xsq partials
  __shared__ float xsq[64];
  __shared__ int   bcomb[64];

  float* es = esbuf;
  float4* es4 = reinterpret_cast<float4*>(esbuf);

  const int t    = threadIdx.x;
  const int lane = t & 63;
  const int w    = t >> 6;                               // 0..3
  const int wu   = __builtin_amdgcn_readfirstlane(w);    // uniform wave id

  const int blk = blockIdx.x;          // 1024
  const int b   = blk >> 4;            // image
  const int s0  = (blk & 15) << 6;     // 64-position window
  const size_t xbase = (size_t)b * (HD * HW) + s0;

  // ---- xsq partials: thread (pos=t&63, g=w) runs chains j=2g,2g+1
  //      (numpy pairwise-8 level-0/1, contract off, exact structure)
  {
    #pragma clang fp contract(off)
    const int pos = t & 63, g = w;
    const float* __restrict__ xp0 = x + xbase + pos;
    float v = xp0[(size_t)(2 * g) * HW];
    float r0 = v * v;
    float u = xp0[(size_t)(2 * g + 1) * HW];
    float r1 = u * u;
    #pragma unroll
    for (int m = 1; m < 8; ++m) {
      v = xp0[(size_t)(2 * g + 8 * m) * HW];
      r0 = r0 + v * v;
      u = xp0[(size_t)(2 * g + 1 + 8 * m) * HW];
      r1 = r1 + u * u;
    }
    sp[g * 64 + pos] = r0 + r1;        // s_g = r[2g] + r[2g+1]
  }

  // ---- accumulator: acc2[pos-pair][code j] == -2*cross (fma chain over c)
  f32x2 acc2[8][8];                    // 128 VGPRs
  #pragma unroll
  for (int pp = 0; pp < 8; ++pp)
    #pragma unroll
    for (int j = 0; j < 8; ++j) acc2[pp][j] = (f32x2)(0.f);

  const float* __restrict__ xw = x + xbase + 16 * wu;    // uniform base
  const float4* __restrict__ g4 = reinterpret_cast<const float4*>(epT);
  const int el = 4 * lane;             // lane's first-code offset in a c-row

  #pragma unroll 1
  for (int ch = 0; ch < 4; ++ch) {
    __syncthreads();                   // es free (prev chunk consumed; ch0: sp done)
    #pragma unroll
    for (int i = 0; i < 8; ++i) {      // 2048 float4 = 32 KB, lane-contiguous
      __builtin_amdgcn_global_load_lds(
          (const __attribute__((address_space(1))) void*)(g4 + (size_t)ch * 2048 + i * 256 + t),
          (__attribute__((address_space(3))) void*)(es4 + i * 256 + t),
          16, 0, 0);
    }
    __builtin_amdgcn_s_waitcnt(0xF70); // vmcnt(0): own DMA done
    __syncthreads();                   // everyone's DMA done

    if (ch == 0 && t < 64) {           // finish xsq tree while others compute
      #pragma clang fp contract(off)
      xsq[t] = (sp[t] + sp[64 + t]) + (sp[128 + t] + sp[192 + t]);
    }

    #pragma unroll 2
    for (int cc = 0; cc < 16; ++cc) {
      const int c = ch * 16 + cc;
      // x: wave-uniform 64B load (16 positions) -> scalar regs
      const f32x16 xv = *reinterpret_cast<const f32x16*>(xw + (size_t)c * HW);
      // e: 2 conflict-free ds_read_b128 (codes 4l..4l+3 and 256+4l..+3)
      const f32x4 e0 = *reinterpret_cast<const f32x4*>(es + cc * NE + el);
      const f32x4 e1 = *reinterpret_cast<const f32x4*>(es + cc * NE + 256 + el);
      const f32x2 ep[4] = {e0.lo, e0.hi, e1.lo, e1.hi};
      #pragma unroll
      for (int pp = 0; pp < 8; ++pp) {
        const f32x2 xp = (f32x2){xv[2 * pp], xv[2 * pp + 1]};
        #pragma unroll
        for (int jp = 0; jp < 4; ++jp) {
          // code 2jp  : e-pair LOW dword broadcast to both halves
          asm("v_pk_fma_f32 %0, %1, %2, %0 op_sel:[0,0,0] op_sel_hi:[1,0,1]"
              : "+v"(acc2[pp][2 * jp]) : "s"(xp), "v"(ep[jp]));
          // code 2jp+1: e-pair HIGH dword broadcast to both halves
          asm("v_pk_fma_f32 %0, %1, %2, %0 op_sel:[0,1,0] op_sel_hi:[1,1,1]"
              : "+v"(acc2[pp][2 * jp + 1]) : "s"(xp), "v"(ep[jp]));
        }
      }
    }
  }
  __syncthreads();                     // es consumed; safe to overlay combine

  // ---- per-lane argmin over its 8 codes, straight into combine scratch.
  //      Lane l codes: j<4 -> 4l+j ; j>=4 -> 256+4l+(j-4). Ascending j ==
  //      ascending code => strict < is first-index-wins.
  const f32x4 eq0 = *reinterpret_cast<const f32x4*>(esq + el);
  const f32x4 eq1 = *reinterpret_cast<const f32x4*>(esq + 256 + el);
  const float esv[8] = {eq0[0], eq0[1], eq0[2], eq0[3],
                        eq1[0], eq1[1], eq1[2], eq1[3]};
  float* cwp = esbuf + w * 2304 + lane * 36;   // [w][lane][16 pairs]
  #pragma unroll
  for (int pi = 0; pi < 16; ++pi) {
    const float xq = xsq[16 * w + pi];         // wave-uniform LDS broadcast
    const int pp = pi >> 1, ph = pi & 1;
    float bd = __builtin_inff();
    int   bi = 0x7fffffff;
    #pragma unroll
    for (int j = 0; j < 8; ++j) {
      const float d = (xq + esv[j]) + acc2[pp][j][ph];
      const int ci = (j < 4) ? (el + j) : (252 + el + j);
      if (d < bd) { bd = d; bi = ci; }
    }
    *reinterpret_cast<f32x2*>(cwp + 2 * pi) =
        (f32x2){bd, __int_as_float(bi)};
  }

  // ---- within-wave reduce (same-wave LDS ops are in-order; no barrier):
  //      stage 1: lane (pi=l&15, qq=l>>4) scans 16 lanes of quarter qq.
  //      stage 2: lanes 0..15 merge the 4 quarters. Lexicographic (d,idx).
  {
    const int pi = lane & 15, qq = lane >> 4;
    const float* crd = esbuf + w * 2304 + qq * 16 * 36;
    float bd = __builtin_inff();
    int   bi = 0x7fffffff;
    #pragma unroll
    for (int i = 0; i < 16; ++i) {
      const f32x2 pr = *reinterpret_cast<const f32x2*>(crd + i * 36 + 2 * pi);
      const float d = pr[0];
      const int idx = __float_as_int(pr[1]);
      if (d < bd || (d == bd && idx < bi)) { bd = d; bi = idx; }
    }
    *reinterpret_cast<f32x2*>(part + ((w * 4 + qq) * 16 + pi) * 2) =
        (f32x2){bd, __int_as_float(bi)};
    if (lane < 16) {
      float bd2 = __builtin_inff();
      int   bi2 = 0x7fffffff;
      #pragma unroll
      for (int q2 = 0; q2 < 4; ++q2) {
        const f32x2 pr = *reinterpret_cast<const f32x2*>(part + ((w * 4 + q2) * 16 + lane) * 2);
        const float d = pr[0];
        const int idx = __float_as_int(pr[1]);
        if (d < bd2 || (d == bd2 && idx < bi2)) { bd2 = d; bi2 = idx; }
      }
      bcomb[w * 16 + lane] = bi2;
    }
  }
  __syncthreads();

  // ---- gather winning codebook rows (L2-hot), coalesced stores
  {
    const int pos = t & 63, cr = t >> 6;
    const int idx = bcomb[pos];
    const float* __restrict__ eq = e + idx * HD;
    #pragma unroll
    for (int i = 0; i < 16; ++i) {
      const int c = cr * 16 + i;
      out[xbase + (size_t)c * HW + pos] = eq[c];
    }
  }
}

extern "C" void kernel_launch(void* const* d_in, const int* in_sizes, int n_in,
                              void* d_out, int out_size, void* d_ws, size_t ws_size,
                              hipStream_t stream) {
  const float* x = (const float*)d_in[0];   // (64, 64, 32, 32) fp32
  const float* e = (const float*)d_in[1];   // (512, 64) fp32
  float* epT = (float*)d_ws;                // 64*512 floats: -2*e transposed
  float* esq = epT + HD * NE;               // 512 floats
  float* out = (float*)d_out;

  vq_prep_kernel<<<130, 256, 0, stream>>>(e, epT, esq);
  vq_main_kernel<<<1024, 256, 0, stream>>>(x, epT, esq, e, out);
}